// Round 15
// baseline (209.782 us; speedup 1.0000x reference)
//
#include <hip/hip_runtime.h>
#include <hip/hip_bf16.h>
#include <math.h>

#define T_DIM 2048
#define B_DIM 2
#define D_DIM 256
#define TC 512
#define KV_LEN 2560   // TC + T

typedef __attribute__((ext_vector_type(8))) short bf16x8;
typedef __attribute__((ext_vector_type(4))) float f32x4;
typedef unsigned short ush;

__device__ __forceinline__ float rope_angle(int pos, int j) {
    float inv = powf(10000.0f, -(float)j * (1.0f / 32.0f));
    return (float)pos * inv;
}

// ---------------------------------------------------------------------------
// K0: prep — fragment-linear bf16 hi/lo tiles + folded weights (R14, verified).
// gid regions: [0,262144) Ap | [262144,294912) Bp | [294912,344064) Bc |
// [344064,409600) Wcomb->Bo | [409600,409856) biascomb.
// ---------------------------------------------------------------------------
__global__ __launch_bounds__(256) void k_prep(
    const float* __restrict__ H, const float* __restrict__ W_Q,
    const float* __restrict__ W_KV, const float* __restrict__ W_DQ,
    const float* __restrict__ W_IUQ, const float* __restrict__ W_w,
    const float* __restrict__ Wc_comp, const float* __restrict__ Wc_idx,
    const float* __restrict__ Wg0, const float* __restrict__ bg0,
    const float* __restrict__ Wg1, const float* __restrict__ bg1,
    const float* __restrict__ Wout, const float* __restrict__ bout,
    ush* __restrict__ Ap, ush* __restrict__ Bp, ush* __restrict__ Bc,
    ush* __restrict__ Bo, float* __restrict__ biascomb)
{
    int gid = blockIdx.x * 256 + threadIdx.x;
    float vals[8];
    ush* dst;
    bool lo_part;

    if (gid < 262144) {
        int tile = gid >> 10;
        int c = (gid >> 6) & 15;
        int l = gid & 63;
        int bt = tile * 16 + (l & 15);
        int kb = (c & 7) * 32 + (l >> 4) * 8;
        const float* src = H + (size_t)bt * 256 + kb;
#pragma unroll
        for (int j = 0; j < 8; ++j) vals[j] = src[j];
        lo_part = (c >= 8);
        dst = Ap + (size_t)gid * 8;
    } else if (gid < 294912) {
        // Bp (N=512): [W_Q | W_KV | W_DQ@W_IUQ | W_DQ@W_w | 0-pad]
        int g = gid - 262144;
        int tile = g >> 10;
        int c = (g >> 6) & 15;
        int l = g & 63;
        int n = tile * 16 + (l & 15);
        int kb = (c & 7) * 32 + (l >> 4) * 8;
#pragma unroll
        for (int j = 0; j < 8; ++j) {
            int k = kb + j;
            float w;
            if (n < 256)      w = W_Q[(size_t)k * 256 + n];
            else if (n < 320) w = W_KV[(size_t)k * 64 + (n - 256)];
            else if (n < 448) {
                w = 0.f;
                for (int i = 0; i < 64; ++i)
                    w = fmaf(W_DQ[(size_t)k * 64 + i], W_IUQ[(size_t)i * 128 + (n - 320)], w);
            } else if (n < 452) {
                w = 0.f;
                for (int i = 0; i < 64; ++i)
                    w = fmaf(W_DQ[(size_t)k * 64 + i], W_w[(size_t)i * 4 + (n - 448)], w);
            } else {
                w = 0.f;
            }
            vals[j] = w;
        }
        lo_part = (c >= 8);
        dst = Bp + (size_t)g * 8;
    } else if (gid < 344064) {
        int g = gid - 294912;
        int tile = g >> 13;
        int c = (g >> 6) & 127;
        int l = g & 63;
        int n = tile * 16 + (l & 15);
        int k2b = (c & 63) * 32 + (l >> 4) * 8;
#pragma unroll
        for (int j = 0; j < 8; ++j) {
            int k = k2b + j;
            vals[j] = (n < 64) ? Wc_comp[(size_t)k * 64 + n]
                               : Wc_idx[(size_t)k * 32 + (n - 64)];
        }
        lo_part = (c >= 64);
        dst = Bc + (size_t)g * 8;
    } else if (gid < 409600) {
        int g = gid - 344064;
        int k = g >> 8;
        int n = g & 255;
        float acc = 0.f;
        if (k < 128) {
            for (int i = 0; i < 64; ++i)
                acc = fmaf(Wg0[k * 64 + i], Wout[(size_t)i * 256 + n], acc);
        } else {
            for (int i = 0; i < 64; ++i)
                acc = fmaf(Wg1[(k - 128) * 64 + i], Wout[(size_t)(64 + i) * 256 + n], acc);
        }
        __hip_bfloat16 hb = __float2bfloat16(acc);
        float hif = __bfloat162float(hb);
        __hip_bfloat16 lb = __float2bfloat16(acc - hif);
        int tile = n >> 4;
        int chi = k >> 5;
        int lane2 = (n & 15) + 16 * ((k >> 3) & 3);
        int j = k & 7;
        Bo[(size_t)(tile * 16 + chi) * 512 + lane2 * 8 + j] = *(ush*)&hb;
        Bo[(size_t)(tile * 16 + chi + 8) * 512 + lane2 * 8 + j] = *(ush*)&lb;
        return;
    } else if (gid < 409856) {
        int n = gid - 409600;
        float acc = bout[n];
        for (int i = 0; i < 64; ++i) {
            acc = fmaf(bg0[i], Wout[(size_t)i * 256 + n], acc);
            acc = fmaf(bg1[i], Wout[(size_t)(64 + i) * 256 + n], acc);
        }
        biascomb[n] = acc;
        return;
    } else {
        return;
    }

    bf16x8 out8;
#pragma unroll
    for (int j = 0; j < 8; ++j) {
        float x = vals[j];
        __hip_bfloat16 hb = __float2bfloat16(x);
        if (!lo_part) {
            out8[j] = *(short*)&hb;
        } else {
            float hif = __bfloat162float(hb);
            __hip_bfloat16 lb = __float2bfloat16(x - hif);
            out8[j] = *(short*)&lb;
        }
    }
    *(bf16x8*)dst = out8;
}

// ---------------------------------------------------------------------------
// K1: MFMA GEMMs + fused epilogues (both paths).
// [0,512): proj M=32 x N=128, fused Q/slide-KV epilogue (R12, verified).
// [512,544): compress UNSPLIT — M=32 windows x N=96 x K=2048 per block,
// A gathered from Ap (R14, verified), epilogue (RMS/rope -> Kb/Vb, KI) fused
// in-register using the same C/D-layout reduction as the proj path.
// k_epi and the Prec buffer are deleted.
// ---------------------------------------------------------------------------
__global__ __launch_bounds__(64) void k_mfma(
    const ush* __restrict__ Ap, const ush* __restrict__ Bp,
    const ush* __restrict__ Bc,
    const float* __restrict__ g_q, const float* __restrict__ g_k,
    const float* __restrict__ g_v,
    float* __restrict__ Pre, float* __restrict__ KIbuf,
    float* __restrict__ Qr, float* __restrict__ Kbuf, float* __restrict__ Vbuf)
{
    int lane = threadIdx.x;
    int mrow = lane & 15;
    int q = lane >> 4;

    if (blockIdx.x < 512) {
        int p = blockIdx.x;
        int m0 = (p >> 2) * 32;
        int nq = p & 3;
        int n0 = nq * 128;
        int at0 = (m0 >> 4) * 16;
        int bt0n = (n0 >> 4) * 16;

        f32x4 acc[2][8];
#pragma unroll
        for (int mt = 0; mt < 2; ++mt)
#pragma unroll
            for (int nt = 0; nt < 8; ++nt) acc[mt][nt] = (f32x4){0.f, 0.f, 0.f, 0.f};

        for (int c = 0; c < 8; ++c) {
            bf16x8 ahi[2], alo[2], bhi[8], blo[8];
#pragma unroll
            for (int mt = 0; mt < 2; ++mt) {
                ahi[mt] = *(const bf16x8*)(Ap + (size_t)((at0 + mt * 16) + c) * 512 + lane * 8);
                alo[mt] = *(const bf16x8*)(Ap + (size_t)((at0 + mt * 16) + 8 + c) * 512 + lane * 8);
            }
#pragma unroll
            for (int nt = 0; nt < 8; ++nt) {
                bhi[nt] = *(const bf16x8*)(Bp + (size_t)((bt0n + nt * 16) + c) * 512 + lane * 8);
                blo[nt] = *(const bf16x8*)(Bp + (size_t)((bt0n + nt * 16) + 8 + c) * 512 + lane * 8);
            }
#pragma unroll
            for (int mt = 0; mt < 2; ++mt)
#pragma unroll
                for (int nt = 0; nt < 8; ++nt) {
                    acc[mt][nt] = __builtin_amdgcn_mfma_f32_16x16x32_bf16(ahi[mt], bhi[nt], acc[mt][nt], 0, 0, 0);
                    acc[mt][nt] = __builtin_amdgcn_mfma_f32_16x16x32_bf16(ahi[mt], blo[nt], acc[mt][nt], 0, 0, 0);
                    acc[mt][nt] = __builtin_amdgcn_mfma_f32_16x16x32_bf16(alo[mt], bhi[nt], acc[mt][nt], 0, 0, 0);
                }
        }

        if (nq < 2) {
            int h0 = nq * 2, h1 = nq * 2 + 1;
#pragma unroll
            for (int mt = 0; mt < 2; ++mt)
#pragma unroll
                for (int reg = 0; reg < 4; ++reg) {
                    int bt = m0 + 16 * mt + 4 * q + reg;
                    int t = bt & 2047;
                    float ss0 = 0.f, ss1 = 0.f;
#pragma unroll
                    for (int k = 0; k < 4; ++k) {
                        float v0 = acc[mt][k][reg];
                        float v1 = acc[mt][4 + k][reg];
                        ss0 = fmaf(v0, v0, ss0);
                        ss1 = fmaf(v1, v1, ss1);
                    }
#pragma unroll
                    for (int off = 1; off <= 8; off <<= 1) {
                        ss0 += __shfl_xor(ss0, off, 64);
                        ss1 += __shfl_xor(ss1, off, 64);
                    }
                    float sc0 = rsqrtf(ss0 * (1.0f / 64.0f) + 1e-6f);
                    float sc1 = rsqrtf(ss1 * (1.0f / 64.0f) + 1e-6f);
#pragma unroll
                    for (int k = 0; k < 2; ++k) {
                        int jj = 16 * k + mrow;
                        float sa, ca;
                        sincosf(rope_angle(t, jj), &sa, &ca);
                        {
                            float x1 = acc[mt][k][reg] * sc0 * g_q[h0 * 64 + jj];
                            float x2 = acc[mt][k + 2][reg] * sc0 * g_q[h0 * 64 + 32 + jj];
                            Qr[(size_t)bt * 256 + h0 * 64 + jj] = fmaf(x1, ca, -x2 * sa);
                            Qr[(size_t)bt * 256 + h0 * 64 + 32 + jj] = fmaf(x1, sa, x2 * ca);
                        }
                        {
                            float x1 = acc[mt][4 + k][reg] * sc1 * g_q[h1 * 64 + jj];
                            float x2 = acc[mt][4 + k + 2][reg] * sc1 * g_q[h1 * 64 + 32 + jj];
                            Qr[(size_t)bt * 256 + h1 * 64 + jj] = fmaf(x1, ca, -x2 * sa);
                            Qr[(size_t)bt * 256 + h1 * 64 + 32 + jj] = fmaf(x1, sa, x2 * ca);
                        }
                    }
                }
        } else if (nq == 2) {
#pragma unroll
            for (int mt = 0; mt < 2; ++mt)
#pragma unroll
                for (int reg = 0; reg < 4; ++reg) {
                    int bt = m0 + 16 * mt + 4 * q + reg;
                    int b = bt >> 11;
                    int t = bt & 2047;
                    float ss = 0.f;
#pragma unroll
                    for (int k = 0; k < 4; ++k) {
                        float v = acc[mt][k][reg];
                        ss = fmaf(v, v, ss);
                    }
#pragma unroll
                    for (int off = 1; off <= 8; off <<= 1) ss += __shfl_xor(ss, off, 64);
                    float sc = rsqrtf(ss * (1.0f / 64.0f) + 1e-6f);
                    int pos = TC + t;
                    size_t base = ((size_t)b * KV_LEN + pos) * 64;
#pragma unroll
                    for (int k = 0; k < 2; ++k) {
                        int jj = 16 * k + mrow;
                        float sa, ca;
                        sincosf(rope_angle(pos, jj), &sa, &ca);
                        float k1 = acc[mt][k][reg] * sc * g_k[jj];
                        float k2 = acc[mt][k + 2][reg] * sc * g_k[32 + jj];
                        float v1 = acc[mt][k][reg] * sc * g_v[jj];
                        float v2 = acc[mt][k + 2][reg] * sc * g_v[32 + jj];
                        Kbuf[base + jj] = fmaf(k1, ca, -k2 * sa);
                        Kbuf[base + 32 + jj] = fmaf(k1, sa, k2 * ca);
                        Vbuf[base + jj] = fmaf(v1, ca, -v2 * sa);
                        Vbuf[base + 32 + jj] = fmaf(v1, sa, v2 * ca);
                    }
#pragma unroll
                    for (int nt = 4; nt < 8; ++nt)
                        Pre[(size_t)bt * 512 + n0 + 16 * nt + mrow] = acc[mt][nt][reg];
                }
        } else {
#pragma unroll
            for (int mt = 0; mt < 2; ++mt)
#pragma unroll
                for (int nt = 0; nt < 8; ++nt)
#pragma unroll
                    for (int reg = 0; reg < 4; ++reg)
                        Pre[(size_t)(m0 + 16 * mt + 4 * q + reg) * 512 + n0 + 16 * nt + mrow] =
                            acc[mt][nt][reg];
        }
    } else {
        // ------- compress, unsplit K, fused epilogue -------
        int cb = blockIdx.x - 512;
        int m0 = cb * 32;              // window base [0,1024)
        int bb = m0 >> 9;              // batch

        f32x4 acc[2][6];
#pragma unroll
        for (int mt = 0; mt < 2; ++mt)
#pragma unroll
            for (int nt = 0; nt < 6; ++nt) acc[mt][nt] = (f32x4){0.f, 0.f, 0.f, 0.f};

        for (int cc = 0; cc < 64; ++cc) {
            int k2b = cc * 32 + q * 8;
            int row_off = k2b >> 8;
            int kcb = k2b & 255;
            int chA = kcb >> 5;
            int lsub = (kcb >> 3) & 3;

            bf16x8 ahi[2], alo[2], bhi[6], blo[6];
#pragma unroll
            for (int mt = 0; mt < 2; ++mt) {
                int s_loc = (m0 & 511) + 16 * mt + mrow;
                int r_loc = 4 * s_loc + row_off;
                int r_glob = bb * 2048 + r_loc;
                int tileA = r_glob >> 4;
                int laneA = (r_glob & 15) + 16 * lsub;
                bf16x8 h8 = *(const bf16x8*)(Ap + (size_t)(tileA * 16 + chA) * 512 + laneA * 8);
                bf16x8 l8 = *(const bf16x8*)(Ap + (size_t)(tileA * 16 + chA + 8) * 512 + laneA * 8);
                if (r_loc >= T_DIM) {
#pragma unroll
                    for (int j = 0; j < 8; ++j) { h8[j] = 0; l8[j] = 0; }
                }
                ahi[mt] = h8;
                alo[mt] = l8;
            }
#pragma unroll
            for (int nt = 0; nt < 6; ++nt) {
                bhi[nt] = *(const bf16x8*)(Bc + (size_t)(nt * 128 + cc) * 512 + lane * 8);
                blo[nt] = *(const bf16x8*)(Bc + (size_t)(nt * 128 + 64 + cc) * 512 + lane * 8);
            }
#pragma unroll
            for (int mt = 0; mt < 2; ++mt)
#pragma unroll
                for (int nt = 0; nt < 6; ++nt) {
                    acc[mt][nt] = __builtin_amdgcn_mfma_f32_16x16x32_bf16(ahi[mt], bhi[nt], acc[mt][nt], 0, 0, 0);
                    acc[mt][nt] = __builtin_amdgcn_mfma_f32_16x16x32_bf16(ahi[mt], blo[nt], acc[mt][nt], 0, 0, 0);
                    acc[mt][nt] = __builtin_amdgcn_mfma_f32_16x16x32_bf16(alo[mt], bhi[nt], acc[mt][nt], 0, 0, 0);
                }
        }

        // fused comp epilogue: cols 0..63 = KVc (nt 0..3), cols 64..95 = KI.
#pragma unroll
        for (int mt = 0; mt < 2; ++mt)
#pragma unroll
            for (int reg = 0; reg < 4; ++reg) {
                int sg = m0 + 16 * mt + 4 * q + reg;
                int b = sg >> 9;
                int s = sg & 511;
                float ss = 0.f;
#pragma unroll
                for (int k = 0; k < 4; ++k) {
                    float v = acc[mt][k][reg];
                    ss = fmaf(v, v, ss);
                }
#pragma unroll
                for (int off = 1; off <= 8; off <<= 1) ss += __shfl_xor(ss, off, 64);
                float sc = rsqrtf(ss * (1.0f / 64.0f) + 1e-6f);
                size_t base = ((size_t)b * KV_LEN + s) * 64;
#pragma unroll
                for (int k = 0; k < 2; ++k) {
                    int jj = 16 * k + mrow;
                    float sa, ca;
                    sincosf(rope_angle(s, jj), &sa, &ca);
                    float k1 = acc[mt][k][reg] * sc * g_k[jj];
                    float k2 = acc[mt][k + 2][reg] * sc * g_k[32 + jj];
                    float v1 = acc[mt][k][reg] * sc * g_v[jj];
                    float v2 = acc[mt][k + 2][reg] * sc * g_v[32 + jj];
                    Kbuf[base + jj] = fmaf(k1, ca, -k2 * sa);
                    Kbuf[base + 32 + jj] = fmaf(k1, sa, k2 * ca);
                    Vbuf[base + jj] = fmaf(v1, ca, -v2 * sa);
                    Vbuf[base + 32 + jj] = fmaf(v1, sa, v2 * ca);
                }
                KIbuf[((size_t)b * TC + s) * 32 + mrow] = acc[mt][4][reg];
                KIbuf[((size_t)b * TC + s) * 32 + 16 + mrow] = acc[mt][5][reg];
            }
    }
}

// ---------------------------------------------------------------------------
// K3: index scores + exact top-8 (verified). QI/Wiw read from Pre.
// ---------------------------------------------------------------------------
__global__ __launch_bounds__(256) void k_score_topk(
    const float* __restrict__ Pre, const float* __restrict__ KIbuf,
    int* __restrict__ topk)
{
    int tid = threadIdx.x;
    int wv = tid >> 6;
    int lane = tid & 63;
    int bt0 = blockIdx.x * 4;
    int bt = bt0 + wv;
    int b = bt >> 11;
    int t = bt & 2047;

    __shared__ float sQ[4][128];
    __shared__ float sw[4][4];
    __shared__ float sKI[64 * 33];

    const float* pr = Pre + (size_t)bt * 512;
    sQ[wv][lane] = pr[320 + lane];
    sQ[wv][64 + lane] = pr[384 + lane];
    if (lane < 4) sw[wv][lane] = pr[448 + lane];

    const float* KIb = KIbuf + (size_t)b * TC * 32;
    int smax = t >> 2;
    int smax_blk = ((bt0 + 3) & 2047) >> 2;

    float vals[8];
#pragma unroll
    for (int r = 0; r < 8; ++r) vals[r] = -INFINITY;

    for (int r = 0; r < 8; ++r) {
        if (r * 64 > smax_blk) break;
        __syncthreads();
        for (int i = tid; i < 512; i += 256) {
            int row = i >> 3;
            int cseg = (i & 7) * 4;
            float4 v = *(const float4*)(KIb + (size_t)(r * 64 + row) * 32 + cseg);
            float* dstp = &sKI[row * 33 + cseg];
            dstp[0] = v.x; dstp[1] = v.y; dstp[2] = v.z; dstp[3] = v.w;
        }
        __syncthreads();

        int s = r * 64 + lane;
        if (s <= smax) {
            float dd0 = 0.f, dd1 = 0.f, dd2 = 0.f, dd3 = 0.f;
#pragma unroll
            for (int c = 0; c < 32; ++c) {
                float kv = sKI[lane * 33 + c];
                dd0 = fmaf(sQ[wv][c], kv, dd0);
                dd1 = fmaf(sQ[wv][32 + c], kv, dd1);
                dd2 = fmaf(sQ[wv][64 + c], kv, dd2);
                dd3 = fmaf(sQ[wv][96 + c], kv, dd3);
            }
            vals[r] = sw[wv][0] * fmaxf(dd0, 0.f) + sw[wv][1] * fmaxf(dd1, 0.f) +
                      sw[wv][2] * fmaxf(dd2, 0.f) + sw[wv][3] * fmaxf(dd3, 0.f);
        }
    }

    unsigned consumed = 0u;
    for (int k2 = 0; k2 < 8; ++k2) {
        float bv = -INFINITY;
        int bi = 0x7fffffff;
#pragma unroll
        for (int r = 0; r < 8; ++r) {
            if (!(consumed & (1u << r))) {
                int s = lane + 64 * r;
                float v = vals[r];
                if (v > bv || (v == bv && s < bi)) { bv = v; bi = s; }
            }
        }
#pragma unroll
        for (int off = 1; off < 64; off <<= 1) {
            float ov = __shfl_xor(bv, off, 64);
            int oi = __shfl_xor(bi, off, 64);
            if (ov > bv || (ov == bv && oi < bi)) { bv = ov; bi = oi; }
        }
        if ((bi & 63) == lane) consumed |= 1u << (bi >> 6);
        if (lane == 0) topk[(size_t)bt * 8 + k2] = bi;
    }
}

// ---------------------------------------------------------------------------
// K4: attention -> Obuf (R13, verified: shared sliding union staging).
// ---------------------------------------------------------------------------
__global__ __launch_bounds__(1024) void k_attn(
    const float* __restrict__ Qr, const float* __restrict__ Kbuf,
    const float* __restrict__ Vbuf, const int* __restrict__ topk,
    float* __restrict__ Obuf)
{
    int tid = threadIdx.x;
    int lt = tid >> 8;
    int t256 = tid & 255;
    int h = t256 >> 6;
    int lane = tid & 63;
    int bt0 = blockIdx.x * 4;
    int bt = bt0 + lt;
    int b = bt >> 11;
    int t = bt & 2047;
    int t0 = bt0 & 2047;

    __shared__ float sKV[102 * 65];
    __shared__ float sQ[4][256];
    __shared__ int sPos[4][8];
    __shared__ float sP[4][4][24];

    sQ[lt][t256] = Qr[(size_t)bt * 256 + t256];
    if (t256 < 8) sPos[lt][t256] = topk[(size_t)bt * 8 + t256];
    __syncthreads();

    for (int i = tid; i < 1632; i += 1024) {
        int row = i >> 4;
        int seg = (i & 15) << 2;
        const float* srcbase;
        bool ok = true;
        if (row < 38) {
            int idx = (row < 19) ? row : row - 19;
            int sp = t0 - 15 + idx;
            ok = (sp >= 0);
            srcbase = ((row < 19) ? Kbuf : Vbuf) +
                      ((size_t)b * KV_LEN + TC + sp) * 64;
        } else {
            int r = row - 38;
            int ltt = r >> 4;
            int slot = r & 15;
            int pos = sPos[ltt][slot & 7];
            srcbase = ((slot < 8) ? Kbuf : Vbuf) +
                      ((size_t)b * KV_LEN + pos) * 64;
        }
        if (ok) {
            float4 v = *(const float4*)(srcbase + seg);
            float* d = &sKV[row * 65 + seg];
            d[0] = v.x; d[1] = v.y; d[2] = v.z; d[3] = v.w;
        }
    }
    __syncthreads();

    float scv = -INFINITY;
    if (lane < 24) {
        int krow;
        bool valid;
        if (lane < 8) { krow = 38 + lt * 16 + lane; valid = true; }
        else          { krow = lt + 23 - lane; valid = (t - (lane - 8) >= 0); }
        if (valid) {
            float dd = 0.f;
#pragma unroll
            for (int c = 0; c < 64; ++c)
                dd = fmaf(sQ[lt][h * 64 + c], sKV[krow * 65 + c], dd);
            scv = dd * 0.125f;
        }
    }
    float m = scv;
#pragma unroll
    for (int off = 1; off < 64; off <<= 1) m = fmaxf(m, __shfl_xor(m, off, 64));
    float p = expf(scv - m);
    if (scv == -INFINITY) p = 0.f;
    float l = p;
#pragma unroll
    for (int off = 1; off < 64; off <<= 1) l += __shfl_xor(l, off, 64);
    p /= l;
    if (lane < 24) sP[lt][h][lane] = p;

    float o = 0.f;
#pragma unroll
    for (int j2 = 0; j2 < 8; ++j2) {
        int vrow = 38 + lt * 16 + 8 + j2;
        o = fmaf(sP[lt][h][j2], sKV[vrow * 65 + lane], o);
    }
#pragma unroll
    for (int j2 = 8; j2 < 24; ++j2) {
        if (t - (j2 - 8) >= 0) {
            int vrow = 19 + (lt + 23 - j2);
            o = fmaf(sP[lt][h][j2], sKV[vrow * 65 + lane], o);
        }
    }

    int j = lane & 31;
    float sa, ca;
    sincosf(rope_angle(t, j), &sa, &ca);
    float prt = __shfl_xor(o, 32, 64);
    float oo = (lane < 32) ? fmaf(o, ca, prt * sa) : fmaf(-prt, sa, o * ca);
    Obuf[(size_t)bt * 256 + h * 64 + lane] = oo;
}

// ---------------------------------------------------------------------------
// K5: output GEMM out = O @ Wcomb + biascomb (verified).
// ---------------------------------------------------------------------------
__global__ __launch_bounds__(64) void k_out(
    const float* __restrict__ Obuf, const ush* __restrict__ Bo,
    const float* __restrict__ biascomb, float* __restrict__ out)
{
    int lane = threadIdx.x;
    int mrow = lane & 15;
    int q = lane >> 4;
    int p = blockIdx.x;
    int m0 = (p >> 2) * 32;
    int n0 = (p & 3) * 64;
    int bt0n = (n0 >> 4) * 16;

    f32x4 acc[2][4];
#pragma unroll
    for (int mt = 0; mt < 2; ++mt)
#pragma unroll
        for (int nt = 0; nt < 4; ++nt) acc[mt][nt] = (f32x4){0.f, 0.f, 0.f, 0.f};

    for (int c = 0; c < 8; ++c) {
        bf16x8 ahi[2], alo[2], bhi[4], blo[4];
#pragma unroll
        for (int mt = 0; mt < 2; ++mt) {
            const float* src = Obuf + (size_t)(m0 + 16 * mt + mrow) * 256 + c * 32 + 8 * q;
            float4 x0 = *(const float4*)src;
            float4 x1 = *(const float4*)(src + 4);
            float xs[8] = {x0.x, x0.y, x0.z, x0.w, x1.x, x1.y, x1.z, x1.w};
#pragma unroll
            for (int j = 0; j < 8; ++j) {
                __hip_bfloat16 hb = __float2bfloat16(xs[j]);
                float hif = __bfloat162float(hb);
                __hip_bfloat16 lb = __float2bfloat16(xs[j] - hif);
                ahi[mt][j] = *(short*)&hb;
                alo[mt][j] = *(short*)&lb;
            }
        }
#pragma unroll
        for (int nt = 0; nt < 4; ++nt) {
            bhi[nt] = *(const bf16x8*)(Bo + (size_t)((bt0n + nt * 16) + c) * 512 + lane * 8);
            blo[nt] = *(const bf16x8*)(Bo + (size_t)((bt0n + nt * 16) + 8 + c) * 512 + lane * 8);
        }
#pragma unroll
        for (int mt = 0; mt < 2; ++mt)
#pragma unroll
            for (int nt = 0; nt < 4; ++nt) {
                acc[mt][nt] = __builtin_amdgcn_mfma_f32_16x16x32_bf16(ahi[mt], bhi[nt], acc[mt][nt], 0, 0, 0);
                acc[mt][nt] = __builtin_amdgcn_mfma_f32_16x16x32_bf16(ahi[mt], blo[nt], acc[mt][nt], 0, 0, 0);
                acc[mt][nt] = __builtin_amdgcn_mfma_f32_16x16x32_bf16(alo[mt], bhi[nt], acc[mt][nt], 0, 0, 0);
            }
    }

#pragma unroll
    for (int mt = 0; mt < 2; ++mt)
#pragma unroll
        for (int nt = 0; nt < 4; ++nt) {
            float bia = biascomb[n0 + 16 * nt + mrow];
#pragma unroll
            for (int reg = 0; reg < 4; ++reg)
                out[(size_t)(m0 + 16 * mt + 4 * q + reg) * 256 + n0 + 16 * nt + mrow] =
                    acc[mt][nt][reg] + bia;
        }
}

// ---------------------------------------------------------------------------
extern "C" void kernel_launch(void* const* d_in, const int* in_sizes, int n_in,
                              void* d_out, int out_size, void* d_ws, size_t ws_size,
                              hipStream_t stream) {
    const float* H       = (const float*)d_in[0];
    const float* Wc_comp = (const float*)d_in[1];
    const float* Wc_idx  = (const float*)d_in[2];
    const float* W_DQ    = (const float*)d_in[3];
    const float* W_IUQ   = (const float*)d_in[4];
    const float* W_w     = (const float*)d_in[5];
    const float* W_Q     = (const float*)d_in[6];
    const float* W_KV    = (const float*)d_in[7];
    const float* g_q     = (const float*)d_in[8];
    const float* g_k     = (const float*)d_in[9];
    const float* g_v     = (const float*)d_in[10];
    const float* Wg0     = (const float*)d_in[11];
    const float* bg0     = (const float*)d_in[12];
    const float* Wg1     = (const float*)d_in[13];
    const float* bg1     = (const float*)d_in[14];
    const float* Wout    = (const float*)d_in[15];
    const float* bout    = (const float*)d_in[16];

    float* ws = (float*)d_ws;
    float* Qr   = ws;                      // 1048576
    float* KI   = ws + 1048576;            // 32768
    float* Kb   = ws + 1081344;            // 327680
    float* Vb   = ws + 1409024;            // 327680
    float* Pre  = ws + 1736704;            // 4096*512 = 2097152
    float* Obuf = ws + 4227072;            // 4096*256 = 1048576
    int* topkb  = (int*)(ws + 5275648);    // 32768
    ush* Ap = (ush*)(ws + 5308416);        // 262144*8 ush (1048576 f)
    ush* Bp = (ush*)(ws + 8454144);        // 32768*8 ush (131072 f)
    ush* Bc = (ush*)(ws + 8585216);        // 49152*8 ush (196608 f)
    ush* Bo = (ush*)(ws + 8781824);        // 131072 ush (65536 f)
    float* biascomb = ws + 8847360;        // 256

    float* outp = (float*)d_out;

    hipLaunchKernelGGL(k_prep, dim3(1601), dim3(256), 0, stream,
                       H, W_Q, W_KV, W_DQ, W_IUQ, W_w, Wc_comp, Wc_idx,
                       Wg0, bg0, Wg1, bg1, Wout, bout,
                       Ap, Bp, Bc, Bo, biascomb);
    hipLaunchKernelGGL(k_mfma, dim3(544), dim3(64), 0, stream,
                       Ap, Bp, Bc, g_q, g_k, g_v, Pre, KI, Qr, Kb, Vb);
    hipLaunchKernelGGL(k_score_topk, dim3(1024), dim3(256), 0, stream,
                       Pre, KI, topkb);
    hipLaunchKernelGGL(k_attn, dim3(1024), dim3(1024), 0, stream,
                       Qr, Kb, Vb, topkb, Obuf);
    hipLaunchKernelGGL(k_out, dim3(512), dim3(64), 0, stream,
                       Obuf, Bo, biascomb, outp);
}

// Round 16
// 173.042 us; speedup vs baseline: 1.2123x; 1.2123x over previous
//
#include <hip/hip_runtime.h>
#include <hip/hip_bf16.h>
#include <math.h>

#define T_DIM 2048
#define B_DIM 2
#define D_DIM 256
#define TC 512
#define KV_LEN 2560   // TC + T

typedef __attribute__((ext_vector_type(8))) short bf16x8;
typedef __attribute__((ext_vector_type(4))) float f32x4;
typedef unsigned short ush;

__device__ __forceinline__ float wave_sum64(float v) {
#pragma unroll
    for (int off = 32; off > 0; off >>= 1) v += __shfl_xor(v, off, 64);
    return v;
}

__device__ __forceinline__ float rope_angle(int pos, int j) {
    float inv = powf(10000.0f, -(float)j * (1.0f / 32.0f));
    return (float)pos * inv;
}

// ---------------------------------------------------------------------------
// K0: prep — fragment-linear bf16 hi/lo tiles + folded weights (R12, verified).
// ---------------------------------------------------------------------------
__global__ __launch_bounds__(256) void k_prep(
    const float* __restrict__ H, const float* __restrict__ W_Q,
    const float* __restrict__ W_KV, const float* __restrict__ W_DQ,
    const float* __restrict__ W_IUQ, const float* __restrict__ W_w,
    const float* __restrict__ Wc_comp, const float* __restrict__ Wc_idx,
    const float* __restrict__ Wg0, const float* __restrict__ bg0,
    const float* __restrict__ Wg1, const float* __restrict__ bg1,
    const float* __restrict__ Wout, const float* __restrict__ bout,
    ush* __restrict__ Ap, ush* __restrict__ Ac,
    ush* __restrict__ Bp, ush* __restrict__ Bc,
    ush* __restrict__ Bo, float* __restrict__ biascomb)
{
    int gid = blockIdx.x * 256 + threadIdx.x;
    float vals[8];
    ush* dst;
    bool lo_part;

    if (gid < 262144) {
        int tile = gid >> 10;
        int c = (gid >> 6) & 15;
        int l = gid & 63;
        int bt = tile * 16 + (l & 15);
        int kb = (c & 7) * 32 + (l >> 4) * 8;
        const float* src = H + (size_t)bt * 256 + kb;
#pragma unroll
        for (int j = 0; j < 8; ++j) vals[j] = src[j];
        lo_part = (c >= 8);
        dst = Ap + (size_t)gid * 8;
    } else if (gid < 786432) {
        int g = gid - 262144;
        int tile = g >> 13;
        int c = (g >> 6) & 127;
        int l = g & 63;
        int m = tile * 16 + (l & 15);
        int s = m & 511;
        int b = m >> 9;
        int k2b = (c & 63) * 32 + (l >> 4) * 8;
        int r4 = 4 * s + (k2b >> 8);
        int col = k2b & 255;
        if (r4 < T_DIM) {
            const float* src = H + ((size_t)b * T_DIM + r4) * 256 + col;
#pragma unroll
            for (int j = 0; j < 8; ++j) vals[j] = src[j];
        } else {
#pragma unroll
            for (int j = 0; j < 8; ++j) vals[j] = 0.f;
        }
        lo_part = (c >= 64);
        dst = Ac + (size_t)g * 8;
    } else if (gid < 819200) {
        // Bp (N=512): [W_Q | W_KV | W_DQ@W_IUQ | W_DQ@W_w | 0-pad]
        int g = gid - 786432;
        int tile = g >> 10;
        int c = (g >> 6) & 15;
        int l = g & 63;
        int n = tile * 16 + (l & 15);
        int kb = (c & 7) * 32 + (l >> 4) * 8;
#pragma unroll
        for (int j = 0; j < 8; ++j) {
            int k = kb + j;
            float w;
            if (n < 256)      w = W_Q[(size_t)k * 256 + n];
            else if (n < 320) w = W_KV[(size_t)k * 64 + (n - 256)];
            else if (n < 448) {
                w = 0.f;
                for (int i = 0; i < 64; ++i)
                    w = fmaf(W_DQ[(size_t)k * 64 + i], W_IUQ[(size_t)i * 128 + (n - 320)], w);
            } else if (n < 452) {
                w = 0.f;
                for (int i = 0; i < 64; ++i)
                    w = fmaf(W_DQ[(size_t)k * 64 + i], W_w[(size_t)i * 4 + (n - 448)], w);
            } else {
                w = 0.f;
            }
            vals[j] = w;
        }
        lo_part = (c >= 8);
        dst = Bp + (size_t)g * 8;
    } else if (gid < 868352) {
        int g = gid - 819200;
        int tile = g >> 13;
        int c = (g >> 6) & 127;
        int l = g & 63;
        int n = tile * 16 + (l & 15);
        int k2b = (c & 63) * 32 + (l >> 4) * 8;
#pragma unroll
        for (int j = 0; j < 8; ++j) {
            int k = k2b + j;
            vals[j] = (n < 64) ? Wc_comp[(size_t)k * 64 + n]
                               : Wc_idx[(size_t)k * 32 + (n - 64)];
        }
        lo_part = (c >= 64);
        dst = Bc + (size_t)g * 8;
    } else if (gid < 933888) {
        int g = gid - 868352;
        int k = g >> 8;
        int n = g & 255;
        float acc = 0.f;
        if (k < 128) {
            for (int i = 0; i < 64; ++i)
                acc = fmaf(Wg0[k * 64 + i], Wout[(size_t)i * 256 + n], acc);
        } else {
            for (int i = 0; i < 64; ++i)
                acc = fmaf(Wg1[(k - 128) * 64 + i], Wout[(size_t)(64 + i) * 256 + n], acc);
        }
        __hip_bfloat16 hb = __float2bfloat16(acc);
        float hif = __bfloat162float(hb);
        __hip_bfloat16 lb = __float2bfloat16(acc - hif);
        int tile = n >> 4;
        int chi = k >> 5;
        int lane2 = (n & 15) + 16 * ((k >> 3) & 3);
        int j = k & 7;
        Bo[(size_t)(tile * 16 + chi) * 512 + lane2 * 8 + j] = *(ush*)&hb;
        Bo[(size_t)(tile * 16 + chi + 8) * 512 + lane2 * 8 + j] = *(ush*)&lb;
        return;
    } else if (gid < 934144) {
        int n = gid - 933888;
        float acc = bout[n];
        for (int i = 0; i < 64; ++i) {
            acc = fmaf(bg0[i], Wout[(size_t)i * 256 + n], acc);
            acc = fmaf(bg1[i], Wout[(size_t)(64 + i) * 256 + n], acc);
        }
        biascomb[n] = acc;
        return;
    } else {
        return;
    }

    bf16x8 out8;
#pragma unroll
    for (int j = 0; j < 8; ++j) {
        float x = vals[j];
        __hip_bfloat16 hb = __float2bfloat16(x);
        if (!lo_part) {
            out8[j] = *(short*)&hb;
        } else {
            float hif = __bfloat162float(hb);
            __hip_bfloat16 lb = __float2bfloat16(x - hif);
            out8[j] = *(short*)&lb;
        }
    }
    *(bf16x8*)dst = out8;
}

// ---------------------------------------------------------------------------
// K1: MFMA GEMMs + fused proj epilogue (R12, verified).
// ---------------------------------------------------------------------------
__global__ __launch_bounds__(64) void k_mfma(
    const ush* __restrict__ Ap, const ush* __restrict__ Ac,
    const ush* __restrict__ Bp, const ush* __restrict__ Bc,
    const float* __restrict__ g_q, const float* __restrict__ g_k,
    const float* __restrict__ g_v,
    float* __restrict__ Pre, float* __restrict__ Prec_part,
    float* __restrict__ Qr, float* __restrict__ Kbuf, float* __restrict__ Vbuf)
{
    int lane = threadIdx.x;
    int mrow = lane & 15;
    int q = lane >> 4;

    if (blockIdx.x < 512) {
        int p = blockIdx.x;
        int m0 = (p >> 2) * 32;
        int nq = p & 3;
        int n0 = nq * 128;
        int at0 = (m0 >> 4) * 16;
        int bt0n = (n0 >> 4) * 16;

        f32x4 acc[2][8];
#pragma unroll
        for (int mt = 0; mt < 2; ++mt)
#pragma unroll
            for (int nt = 0; nt < 8; ++nt) acc[mt][nt] = (f32x4){0.f, 0.f, 0.f, 0.f};

        for (int c = 0; c < 8; ++c) {
            bf16x8 ahi[2], alo[2], bhi[8], blo[8];
#pragma unroll
            for (int mt = 0; mt < 2; ++mt) {
                ahi[mt] = *(const bf16x8*)(Ap + (size_t)((at0 + mt * 16) + c) * 512 + lane * 8);
                alo[mt] = *(const bf16x8*)(Ap + (size_t)((at0 + mt * 16) + 8 + c) * 512 + lane * 8);
            }
#pragma unroll
            for (int nt = 0; nt < 8; ++nt) {
                bhi[nt] = *(const bf16x8*)(Bp + (size_t)((bt0n + nt * 16) + c) * 512 + lane * 8);
                blo[nt] = *(const bf16x8*)(Bp + (size_t)((bt0n + nt * 16) + 8 + c) * 512 + lane * 8);
            }
#pragma unroll
            for (int mt = 0; mt < 2; ++mt)
#pragma unroll
                for (int nt = 0; nt < 8; ++nt) {
                    acc[mt][nt] = __builtin_amdgcn_mfma_f32_16x16x32_bf16(ahi[mt], bhi[nt], acc[mt][nt], 0, 0, 0);
                    acc[mt][nt] = __builtin_amdgcn_mfma_f32_16x16x32_bf16(ahi[mt], blo[nt], acc[mt][nt], 0, 0, 0);
                    acc[mt][nt] = __builtin_amdgcn_mfma_f32_16x16x32_bf16(alo[mt], bhi[nt], acc[mt][nt], 0, 0, 0);
                }
        }

        if (nq < 2) {
            int h0 = nq * 2, h1 = nq * 2 + 1;
#pragma unroll
            for (int mt = 0; mt < 2; ++mt)
#pragma unroll
                for (int reg = 0; reg < 4; ++reg) {
                    int bt = m0 + 16 * mt + 4 * q + reg;
                    int t = bt & 2047;
                    float ss0 = 0.f, ss1 = 0.f;
#pragma unroll
                    for (int k = 0; k < 4; ++k) {
                        float v0 = acc[mt][k][reg];
                        float v1 = acc[mt][4 + k][reg];
                        ss0 = fmaf(v0, v0, ss0);
                        ss1 = fmaf(v1, v1, ss1);
                    }
#pragma unroll
                    for (int off = 1; off <= 8; off <<= 1) {
                        ss0 += __shfl_xor(ss0, off, 64);
                        ss1 += __shfl_xor(ss1, off, 64);
                    }
                    float sc0 = rsqrtf(ss0 * (1.0f / 64.0f) + 1e-6f);
                    float sc1 = rsqrtf(ss1 * (1.0f / 64.0f) + 1e-6f);
#pragma unroll
                    for (int k = 0; k < 2; ++k) {
                        int jj = 16 * k + mrow;
                        float sa, ca;
                        sincosf(rope_angle(t, jj), &sa, &ca);
                        {
                            float x1 = acc[mt][k][reg] * sc0 * g_q[h0 * 64 + jj];
                            float x2 = acc[mt][k + 2][reg] * sc0 * g_q[h0 * 64 + 32 + jj];
                            Qr[(size_t)bt * 256 + h0 * 64 + jj] = fmaf(x1, ca, -x2 * sa);
                            Qr[(size_t)bt * 256 + h0 * 64 + 32 + jj] = fmaf(x1, sa, x2 * ca);
                        }
                        {
                            float x1 = acc[mt][4 + k][reg] * sc1 * g_q[h1 * 64 + jj];
                            float x2 = acc[mt][4 + k + 2][reg] * sc1 * g_q[h1 * 64 + 32 + jj];
                            Qr[(size_t)bt * 256 + h1 * 64 + jj] = fmaf(x1, ca, -x2 * sa);
                            Qr[(size_t)bt * 256 + h1 * 64 + 32 + jj] = fmaf(x1, sa, x2 * ca);
                        }
                    }
                }
        } else if (nq == 2) {
#pragma unroll
            for (int mt = 0; mt < 2; ++mt)
#pragma unroll
                for (int reg = 0; reg < 4; ++reg) {
                    int bt = m0 + 16 * mt + 4 * q + reg;
                    int b = bt >> 11;
                    int t = bt & 2047;
                    float ss = 0.f;
#pragma unroll
                    for (int k = 0; k < 4; ++k) {
                        float v = acc[mt][k][reg];
                        ss = fmaf(v, v, ss);
                    }
#pragma unroll
                    for (int off = 1; off <= 8; off <<= 1) ss += __shfl_xor(ss, off, 64);
                    float sc = rsqrtf(ss * (1.0f / 64.0f) + 1e-6f);
                    int pos = TC + t;
                    size_t base = ((size_t)b * KV_LEN + pos) * 64;
#pragma unroll
                    for (int k = 0; k < 2; ++k) {
                        int jj = 16 * k + mrow;
                        float sa, ca;
                        sincosf(rope_angle(pos, jj), &sa, &ca);
                        float k1 = acc[mt][k][reg] * sc * g_k[jj];
                        float k2 = acc[mt][k + 2][reg] * sc * g_k[32 + jj];
                        float v1 = acc[mt][k][reg] * sc * g_v[jj];
                        float v2 = acc[mt][k + 2][reg] * sc * g_v[32 + jj];
                        Kbuf[base + jj] = fmaf(k1, ca, -k2 * sa);
                        Kbuf[base + 32 + jj] = fmaf(k1, sa, k2 * ca);
                        Vbuf[base + jj] = fmaf(v1, ca, -v2 * sa);
                        Vbuf[base + 32 + jj] = fmaf(v1, sa, v2 * ca);
                    }
#pragma unroll
                    for (int nt = 4; nt < 8; ++nt)
                        Pre[(size_t)bt * 512 + n0 + 16 * nt + mrow] = acc[mt][nt][reg];
                }
        } else {
#pragma unroll
            for (int mt = 0; mt < 2; ++mt)
#pragma unroll
                for (int nt = 0; nt < 8; ++nt)
#pragma unroll
                    for (int reg = 0; reg < 4; ++reg)
                        Pre[(size_t)(m0 + 16 * mt + 4 * q + reg) * 512 + n0 + 16 * nt + mrow] =
                            acc[mt][nt][reg];
        }
    } else {
        int cb = blockIdx.x - 512;
        int m0 = (cb >> 2) * 32;
        int q4 = cb & 3;
        int at0 = (m0 >> 4) * 128;

        f32x4 acc[2][6];
#pragma unroll
        for (int mt = 0; mt < 2; ++mt)
#pragma unroll
            for (int nt = 0; nt < 6; ++nt) acc[mt][nt] = (f32x4){0.f, 0.f, 0.f, 0.f};

        for (int cl = 0; cl < 16; ++cl) {
            int c = q4 * 16 + cl;
            bf16x8 ahi[2], alo[2], bhi[6], blo[6];
#pragma unroll
            for (int mt = 0; mt < 2; ++mt) {
                ahi[mt] = *(const bf16x8*)(Ac + (size_t)((at0 + mt * 128) + c) * 512 + lane * 8);
                alo[mt] = *(const bf16x8*)(Ac + (size_t)((at0 + mt * 128) + 64 + c) * 512 + lane * 8);
            }
#pragma unroll
            for (int nt = 0; nt < 6; ++nt) {
                bhi[nt] = *(const bf16x8*)(Bc + (size_t)(nt * 128 + c) * 512 + lane * 8);
                blo[nt] = *(const bf16x8*)(Bc + (size_t)(nt * 128 + 64 + c) * 512 + lane * 8);
            }
#pragma unroll
            for (int mt = 0; mt < 2; ++mt)
#pragma unroll
                for (int nt = 0; nt < 6; ++nt) {
                    acc[mt][nt] = __builtin_amdgcn_mfma_f32_16x16x32_bf16(ahi[mt], bhi[nt], acc[mt][nt], 0, 0, 0);
                    acc[mt][nt] = __builtin_amdgcn_mfma_f32_16x16x32_bf16(ahi[mt], blo[nt], acc[mt][nt], 0, 0, 0);
                    acc[mt][nt] = __builtin_amdgcn_mfma_f32_16x16x32_bf16(alo[mt], bhi[nt], acc[mt][nt], 0, 0, 0);
                }
        }

        float* dst = Prec_part + (size_t)q4 * (1024 * 96);
#pragma unroll
        for (int mt = 0; mt < 2; ++mt)
#pragma unroll
            for (int nt = 0; nt < 6; ++nt)
#pragma unroll
                for (int reg = 0; reg < 4; ++reg)
                    dst[(size_t)(m0 + 16 * mt + 4 * q + reg) * 96 + 16 * nt + mrow] =
                        acc[mt][nt][reg];
    }
}

// ---------------------------------------------------------------------------
// K2: comp epilogue only (R12, verified). 256 blocks.
// ---------------------------------------------------------------------------
__global__ __launch_bounds__(256) void k_epi(
    const float* __restrict__ Prec_part,
    const float* __restrict__ g_k, const float* __restrict__ g_v,
    float* __restrict__ KIbuf, float* __restrict__ Kbuf, float* __restrict__ Vbuf)
{
    int tid = threadIdx.x;
    int wv = tid >> 6;
    int lane = tid & 63;
    int sg = blockIdx.x * 4 + wv;
    int b = sg >> 9;
    int s = sg & 511;

    const float* p0 = Prec_part + (size_t)sg * 96;
    float kvv = p0[lane] + p0[98304 + lane] + p0[2 * 98304 + lane] + p0[3 * 98304 + lane];

    float ss = wave_sum64(kvv * kvv);
    float sc = rsqrtf(ss * (1.0f / 64.0f) + 1e-6f);
    float kk = kvv * sc * g_k[lane];
    float vv = kvv * sc * g_v[lane];
    int j = lane & 31;
    float sa, ca;
    sincosf(rope_angle(s, j), &sa, &ca);
    float pk = __shfl_xor(kk, 32, 64);
    float pv = __shfl_xor(vv, 32, 64);
    float ko = (lane < 32) ? fmaf(kk, ca, -pk * sa) : fmaf(pk, sa, kk * ca);
    float vo = (lane < 32) ? fmaf(vv, ca, -pv * sa) : fmaf(pv, sa, vv * ca);
    size_t off = ((size_t)b * KV_LEN + s) * 64 + lane;
    Kbuf[off] = ko;
    Vbuf[off] = vo;

    if (lane < 32) {
        float a = p0[64 + lane] + p0[98304 + 64 + lane] +
                  p0[2 * 98304 + 64 + lane] + p0[3 * 98304 + 64 + lane];
        KIbuf[((size_t)b * TC + s) * 32 + lane] = a;
    }
}

// ---------------------------------------------------------------------------
// K3: index scores + exact top-8 (verified). QI/Wiw read from Pre.
// ---------------------------------------------------------------------------
__global__ __launch_bounds__(256) void k_score_topk(
    const float* __restrict__ Pre, const float* __restrict__ KIbuf,
    int* __restrict__ topk)
{
    int tid = threadIdx.x;
    int wv = tid >> 6;
    int lane = tid & 63;
    int bt0 = blockIdx.x * 4;
    int bt = bt0 + wv;
    int b = bt >> 11;
    int t = bt & 2047;

    __shared__ float sQ[4][128];
    __shared__ float sw[4][4];
    __shared__ float sKI[64 * 33];

    const float* pr = Pre + (size_t)bt * 512;
    sQ[wv][lane] = pr[320 + lane];
    sQ[wv][64 + lane] = pr[384 + lane];
    if (lane < 4) sw[wv][lane] = pr[448 + lane];

    const float* KIb = KIbuf + (size_t)b * TC * 32;
    int smax = t >> 2;
    int smax_blk = ((bt0 + 3) & 2047) >> 2;

    float vals[8];
#pragma unroll
    for (int r = 0; r < 8; ++r) vals[r] = -INFINITY;

    for (int r = 0; r < 8; ++r) {
        if (r * 64 > smax_blk) break;
        __syncthreads();
        for (int i = tid; i < 512; i += 256) {
            int row = i >> 3;
            int cseg = (i & 7) * 4;
            float4 v = *(const float4*)(KIb + (size_t)(r * 64 + row) * 32 + cseg);
            float* dstp = &sKI[row * 33 + cseg];
            dstp[0] = v.x; dstp[1] = v.y; dstp[2] = v.z; dstp[3] = v.w;
        }
        __syncthreads();

        int s = r * 64 + lane;
        if (s <= smax) {
            float dd0 = 0.f, dd1 = 0.f, dd2 = 0.f, dd3 = 0.f;
#pragma unroll
            for (int c = 0; c < 32; ++c) {
                float kv = sKI[lane * 33 + c];
                dd0 = fmaf(sQ[wv][c], kv, dd0);
                dd1 = fmaf(sQ[wv][32 + c], kv, dd1);
                dd2 = fmaf(sQ[wv][64 + c], kv, dd2);
                dd3 = fmaf(sQ[wv][96 + c], kv, dd3);
            }
            vals[r] = sw[wv][0] * fmaxf(dd0, 0.f) + sw[wv][1] * fmaxf(dd1, 0.f) +
                      sw[wv][2] * fmaxf(dd2, 0.f) + sw[wv][3] * fmaxf(dd3, 0.f);
        }
    }

    unsigned consumed = 0u;
    for (int k2 = 0; k2 < 8; ++k2) {
        float bv = -INFINITY;
        int bi = 0x7fffffff;
#pragma unroll
        for (int r = 0; r < 8; ++r) {
            if (!(consumed & (1u << r))) {
                int s = lane + 64 * r;
                float v = vals[r];
                if (v > bv || (v == bv && s < bi)) { bv = v; bi = s; }
            }
        }
#pragma unroll
        for (int off = 1; off < 64; off <<= 1) {
            float ov = __shfl_xor(bv, off, 64);
            int oi = __shfl_xor(bi, off, 64);
            if (ov > bv || (ov == bv && oi < bi)) { bv = ov; bi = oi; }
        }
        if ((bi & 63) == lane) consumed |= 1u << (bi >> 6);
        if (lane == 0) topk[(size_t)bt * 8 + k2] = bi;
    }
}

// ---------------------------------------------------------------------------
// K4: attention -> Obuf (R13, verified: shared sliding union staging).
// ---------------------------------------------------------------------------
__global__ __launch_bounds__(1024) void k_attn(
    const float* __restrict__ Qr, const float* __restrict__ Kbuf,
    const float* __restrict__ Vbuf, const int* __restrict__ topk,
    float* __restrict__ Obuf)
{
    int tid = threadIdx.x;
    int lt = tid >> 8;
    int t256 = tid & 255;
    int h = t256 >> 6;
    int lane = tid & 63;
    int bt0 = blockIdx.x * 4;
    int bt = bt0 + lt;
    int b = bt >> 11;
    int t = bt & 2047;
    int t0 = bt0 & 2047;

    __shared__ float sKV[102 * 65];
    __shared__ float sQ[4][256];
    __shared__ int sPos[4][8];
    __shared__ float sP[4][4][24];

    sQ[lt][t256] = Qr[(size_t)bt * 256 + t256];
    if (t256 < 8) sPos[lt][t256] = topk[(size_t)bt * 8 + t256];
    __syncthreads();

    for (int i = tid; i < 1632; i += 1024) {
        int row = i >> 4;
        int seg = (i & 15) << 2;
        const float* srcbase;
        bool ok = true;
        if (row < 38) {
            int idx = (row < 19) ? row : row - 19;
            int sp = t0 - 15 + idx;
            ok = (sp >= 0);
            srcbase = ((row < 19) ? Kbuf : Vbuf) +
                      ((size_t)b * KV_LEN + TC + sp) * 64;
        } else {
            int r = row - 38;
            int ltt = r >> 4;
            int slot = r & 15;
            int pos = sPos[ltt][slot & 7];
            srcbase = ((slot < 8) ? Kbuf : Vbuf) +
                      ((size_t)b * KV_LEN + pos) * 64;
        }
        if (ok) {
            float4 v = *(const float4*)(srcbase + seg);
            float* d = &sKV[row * 65 + seg];
            d[0] = v.x; d[1] = v.y; d[2] = v.z; d[3] = v.w;
        }
    }
    __syncthreads();

    float scv = -INFINITY;
    if (lane < 24) {
        int krow;
        bool valid;
        if (lane < 8) { krow = 38 + lt * 16 + lane; valid = true; }
        else          { krow = lt + 23 - lane; valid = (t - (lane - 8) >= 0); }
        if (valid) {
            float dd = 0.f;
#pragma unroll
            for (int c = 0; c < 64; ++c)
                dd = fmaf(sQ[lt][h * 64 + c], sKV[krow * 65 + c], dd);
            scv = dd * 0.125f;
        }
    }
    float m = scv;
#pragma unroll
    for (int off = 1; off < 64; off <<= 1) m = fmaxf(m, __shfl_xor(m, off, 64));
    float p = expf(scv - m);
    if (scv == -INFINITY) p = 0.f;
    float l = p;
#pragma unroll
    for (int off = 1; off < 64; off <<= 1) l += __shfl_xor(l, off, 64);
    p /= l;
    if (lane < 24) sP[lt][h][lane] = p;

    float o = 0.f;
#pragma unroll
    for (int j2 = 0; j2 < 8; ++j2) {
        int vrow = 38 + lt * 16 + 8 + j2;
        o = fmaf(sP[lt][h][j2], sKV[vrow * 65 + lane], o);
    }
#pragma unroll
    for (int j2 = 8; j2 < 24; ++j2) {
        if (t - (j2 - 8) >= 0) {
            int vrow = 19 + (lt + 23 - j2);
            o = fmaf(sP[lt][h][j2], sKV[vrow * 65 + lane], o);
        }
    }

    int j = lane & 31;
    float sa, ca;
    sincosf(rope_angle(t, j), &sa, &ca);
    float prt = __shfl_xor(o, 32, 64);
    float oo = (lane < 32) ? fmaf(o, ca, prt * sa) : fmaf(-prt, sa, o * ca);
    Obuf[(size_t)bt * 256 + h * 64 + lane] = oo;
}

// ---------------------------------------------------------------------------
// K5: output GEMM out = O @ Wcomb + biascomb (verified).
// ---------------------------------------------------------------------------
__global__ __launch_bounds__(64) void k_out(
    const float* __restrict__ Obuf, const ush* __restrict__ Bo,
    const float* __restrict__ biascomb, float* __restrict__ out)
{
    int lane = threadIdx.x;
    int mrow = lane & 15;
    int q = lane >> 4;
    int p = blockIdx.x;
    int m0 = (p >> 2) * 32;
    int n0 = (p & 3) * 64;
    int bt0n = (n0 >> 4) * 16;

    f32x4 acc[2][4];
#pragma unroll
    for (int mt = 0; mt < 2; ++mt)
#pragma unroll
        for (int nt = 0; nt < 4; ++nt) acc[mt][nt] = (f32x4){0.f, 0.f, 0.f, 0.f};

    for (int c = 0; c < 8; ++c) {
        bf16x8 ahi[2], alo[2], bhi[4], blo[4];
#pragma unroll
        for (int mt = 0; mt < 2; ++mt) {
            const float* src = Obuf + (size_t)(m0 + 16 * mt + mrow) * 256 + c * 32 + 8 * q;
            float4 x0 = *(const float4*)src;
            float4 x1 = *(const float4*)(src + 4);
            float xs[8] = {x0.x, x0.y, x0.z, x0.w, x1.x, x1.y, x1.z, x1.w};
#pragma unroll
            for (int j = 0; j < 8; ++j) {
                __hip_bfloat16 hb = __float2bfloat16(xs[j]);
                float hif = __bfloat162float(hb);
                __hip_bfloat16 lb = __float2bfloat16(xs[j] - hif);
                ahi[mt][j] = *(short*)&hb;
                alo[mt][j] = *(short*)&lb;
            }
        }
#pragma unroll
        for (int nt = 0; nt < 4; ++nt) {
            bhi[nt] = *(const bf16x8*)(Bo + (size_t)((bt0n + nt * 16) + c) * 512 + lane * 8);
            blo[nt] = *(const bf16x8*)(Bo + (size_t)((bt0n + nt * 16) + 8 + c) * 512 + lane * 8);
        }
#pragma unroll
        for (int mt = 0; mt < 2; ++mt)
#pragma unroll
            for (int nt = 0; nt < 4; ++nt) {
                acc[mt][nt] = __builtin_amdgcn_mfma_f32_16x16x32_bf16(ahi[mt], bhi[nt], acc[mt][nt], 0, 0, 0);
                acc[mt][nt] = __builtin_amdgcn_mfma_f32_16x16x32_bf16(ahi[mt], blo[nt], acc[mt][nt], 0, 0, 0);
                acc[mt][nt] = __builtin_amdgcn_mfma_f32_16x16x32_bf16(alo[mt], bhi[nt], acc[mt][nt], 0, 0, 0);
            }
    }

#pragma unroll
    for (int mt = 0; mt < 2; ++mt)
#pragma unroll
        for (int nt = 0; nt < 4; ++nt) {
            float bia = biascomb[n0 + 16 * nt + mrow];
#pragma unroll
            for (int reg = 0; reg < 4; ++reg)
                out[(size_t)(m0 + 16 * mt + 4 * q + reg) * 256 + n0 + 16 * nt + mrow] =
                    acc[mt][nt][reg] + bia;
        }
}

// ---------------------------------------------------------------------------
extern "C" void kernel_launch(void* const* d_in, const int* in_sizes, int n_in,
                              void* d_out, int out_size, void* d_ws, size_t ws_size,
                              hipStream_t stream) {
    const float* H       = (const float*)d_in[0];
    const float* Wc_comp = (const float*)d_in[1];
    const float* Wc_idx  = (const float*)d_in[2];
    const float* W_DQ    = (const float*)d_in[3];
    const float* W_IUQ   = (const float*)d_in[4];
    const float* W_w     = (const float*)d_in[5];
    const float* W_Q     = (const float*)d_in[6];
    const float* W_KV    = (const float*)d_in[7];
    const float* g_q     = (const float*)d_in[8];
    const float* g_k     = (const float*)d_in[9];
    const float* g_v     = (const float*)d_in[10];
    const float* Wg0     = (const float*)d_in[11];
    const float* bg0     = (const float*)d_in[12];
    const float* Wg1     = (const float*)d_in[13];
    const float* bg1     = (const float*)d_in[14];
    const float* Wout    = (const float*)d_in[15];
    const float* bout    = (const float*)d_in[16];

    float* ws = (float*)d_ws;
    float* Qr   = ws;                      // 1048576
    float* KI   = ws + 1048576;            // 32768
    float* Kb   = ws + 1081344;            // 327680
    float* Vb   = ws + 1409024;            // 327680
    float* Pre  = ws + 1736704;            // 4096*512 = 2097152
    float* Prec = ws + 3833856;            // 4*1024*96 = 393216
    float* Obuf = ws + 4227072;            // 4096*256 = 1048576
    int* topkb  = (int*)(ws + 5275648);    // 32768
    ush* Ap = (ush*)(ws + 5308416);        // 262144*8 ush (1048576 f)
    ush* Ac = (ush*)(ws + 6356992);        // 524288*8 ush (2097152 f)
    ush* Bp = (ush*)(ws + 8454144);        // 32768*8 ush (131072 f)
    ush* Bc = (ush*)(ws + 8585216);        // 49152*8 ush (196608 f)
    ush* Bo = (ush*)(ws + 8781824);        // 131072 ush (65536 f)
    float* biascomb = ws + 8847360;        // 256

    float* outp = (float*)d_out;

    hipLaunchKernelGGL(k_prep, dim3(3649), dim3(256), 0, stream,
                       H, W_Q, W_KV, W_DQ, W_IUQ, W_w, Wc_comp, Wc_idx,
                       Wg0, bg0, Wg1, bg1, Wout, bout,
                       Ap, Ac, Bp, Bc, Bo, biascomb);
    hipLaunchKernelGGL(k_mfma, dim3(640), dim3(64), 0, stream,
                       Ap, Ac, Bp, Bc, g_q, g_k, g_v, Pre, Prec, Qr, Kb, Vb);
    hipLaunchKernelGGL(k_epi, dim3(256), dim3(256), 0, stream,
                       Prec, g_k, g_v, KI, Kb, Vb);
    hipLaunchKernelGGL(k_score_topk, dim3(1024), dim3(256), 0, stream,
                       Pre, KI, topkb);
    hipLaunchKernelGGL(k_attn, dim3(1024), dim3(1024), 0, stream,
                       Qr, Kb, Vb, topkb, Obuf);
    hipLaunchKernelGGL(k_out, dim3(512), dim3(64), 0, stream,
                       Obuf, Bo, biascomb, outp);
}